// Round 1
// baseline (541.132 us; speedup 1.0000x reference)
//
#include <hip/hip_runtime.h>
#include <stdint.h>

typedef __attribute__((ext_vector_type(8))) short bf16x8;   // 8 bf16 in 4 VGPRs
typedef __attribute__((ext_vector_type(4))) float f32x4;    // MFMA C/D frag
typedef __attribute__((ext_vector_type(4))) unsigned short u16x4;

__device__ __forceinline__ unsigned short f2bf(float f) {
  uint32_t u = __builtin_bit_cast(uint32_t, f);
  uint32_t r = (u + 0x7FFFu + ((u >> 16) & 1u)) >> 16;  // round-to-nearest-even
  return (unsigned short)r;
}

// ---------------- Kernel 1: x fp32 -> bf16 ----------------
__global__ __launch_bounds__(256) void cvt_x_kernel(const float4* __restrict__ x,
                                                    u16x4* __restrict__ xb, int n4) {
  int i = blockIdx.x * 256 + threadIdx.x;
  if (i >= n4) return;
  float4 v = x[i];
  u16x4 o;
  o.x = f2bf(v.x); o.y = f2bf(v.y); o.z = f2bf(v.z); o.w = f2bf(v.w);
  xb[i] = o;
}

// ---------------- Kernel 2: gather-dequant into B^T [N][K] bf16 ----------------
// thread -> (k, g): reads labels[k][g], centroids[lab][0..7], writes 8 rows of Bt
// at column k. Within a wave, k is the fast index -> each of the 8 stores is a
// 64-lane x 2B contiguous (128B) segment: coalesced.
__global__ __launch_bounds__(256) void dequant_kernel(const float* __restrict__ centroids,
                                                      const int* __restrict__ labels,
                                                      const float* __restrict__ scale,
                                                      unsigned short* __restrict__ Bt,
                                                      int K, int G) {
  int k = blockIdx.x * 256 + threadIdx.x;   // 0..K-1
  int g = blockIdx.y;                        // 0..G-1
  int lab = labels[(size_t)k * G + g];
  float rs = 1.0f / fmaxf(scale[k], 1e-8f);
  const float4* c = (const float4*)(centroids + (size_t)lab * 8);
  float4 c0 = c[0], c1 = c[1];
  size_t base = (size_t)(g * 8) * (size_t)K + (size_t)k;
  Bt[base + 0 * (size_t)K] = f2bf(c0.x * rs);
  Bt[base + 1 * (size_t)K] = f2bf(c0.y * rs);
  Bt[base + 2 * (size_t)K] = f2bf(c0.z * rs);
  Bt[base + 3 * (size_t)K] = f2bf(c0.w * rs);
  Bt[base + 4 * (size_t)K] = f2bf(c1.x * rs);
  Bt[base + 5 * (size_t)K] = f2bf(c1.y * rs);
  Bt[base + 6 * (size_t)K] = f2bf(c1.z * rs);
  Bt[base + 7 * (size_t)K] = f2bf(c1.w * rs);
}

// ---------------- Kernel 3: bf16 GEMM (A[M][K] x Bt[N][K]) + bias, fp32 out ----
#define BM 128
#define BN 128
#define BK 32

__global__ __launch_bounds__(256, 3) void gemm_bias_kernel(
    const unsigned short* __restrict__ A,   // [M][K] bf16
    const unsigned short* __restrict__ B,   // [N][K] bf16 (B^T layout)
    const float* __restrict__ bias,         // [N]
    float* __restrict__ C,                  // [M][N] fp32
    int M, int N, int K) {
  __shared__ __align__(16) unsigned short sA[BM * BK];  // 8 KB
  __shared__ __align__(16) unsigned short sB[BN * BK];  // 8 KB

  const int tid  = threadIdx.x;
  const int w    = tid >> 6;        // wave 0..3
  const int lane = tid & 63;
  const int ln   = lane & 15;
  const int quad = lane >> 4;
  const int wm   = w >> 1;          // 2x2 wave grid, each wave 64x64
  const int wn   = w & 1;

  const int m0 = blockIdx.y * BM;
  const int n0 = blockIdx.x * BN;

  // staging: tile = 512 x 16B chunks per operand is wrong; each operand tile is
  // 128 rows x 64 B = 512 chunks of 16B? -> 8KB/16B = 512 chunks, but 256
  // threads x 1 chunk x 2 rounds covers it. chunk c: row = c>>2, kq = c&3.
  const int c0 = w * 64 + lane;     // round 0 chunk: 0..255
  const int c1 = 256 + c0;          // round 1 chunk: 256..511

  const unsigned short* gA0 = A + (size_t)(m0 + (c0 >> 2)) * K + (c0 & 3) * 8;
  const unsigned short* gA1 = A + (size_t)(m0 + (c1 >> 2)) * K + (c1 & 3) * 8;
  const unsigned short* gB0 = B + (size_t)(n0 + (c0 >> 2)) * K + (c0 & 3) * 8;
  const unsigned short* gB1 = B + (size_t)(n0 + (c1 >> 2)) * K + (c1 & 3) * 8;

  // wave-uniform LDS bases: chunk (base + lane) lands at base*16 + lane*16
  unsigned short* lA0 = sA + (w * 64) * 8;
  unsigned short* lA1 = sA + (256 + w * 64) * 8;
  unsigned short* lB0 = sB + (w * 64) * 8;
  unsigned short* lB1 = sB + (256 + w * 64) * 8;

  f32x4 acc[4][4];
#pragma unroll
  for (int i = 0; i < 4; ++i)
#pragma unroll
    for (int j = 0; j < 4; ++j)
      acc[i][j] = (f32x4){0.f, 0.f, 0.f, 0.f};

  const int nIter = K / BK;
  for (int it = 0; it < nIter; ++it) {
    __builtin_amdgcn_global_load_lds((__attribute__((address_space(1))) void*)gA0,
                                     (__attribute__((address_space(3))) void*)lA0, 16, 0, 0);
    __builtin_amdgcn_global_load_lds((__attribute__((address_space(1))) void*)gA1,
                                     (__attribute__((address_space(3))) void*)lA1, 16, 0, 0);
    __builtin_amdgcn_global_load_lds((__attribute__((address_space(1))) void*)gB0,
                                     (__attribute__((address_space(3))) void*)lB0, 16, 0, 0);
    __builtin_amdgcn_global_load_lds((__attribute__((address_space(1))) void*)gB1,
                                     (__attribute__((address_space(3))) void*)lB1, 16, 0, 0);
    gA0 += BK; gA1 += BK; gB0 += BK; gB1 += BK;

    __syncthreads();  // drains vmcnt(0): global_load_lds complete for all waves

    bf16x8 af[4], bfr[4];
#pragma unroll
    for (int mi = 0; mi < 4; ++mi)
      af[mi] = *(const bf16x8*)(sA + (wm * 64 + mi * 16 + ln) * BK + quad * 8);
#pragma unroll
    for (int ni = 0; ni < 4; ++ni)
      bfr[ni] = *(const bf16x8*)(sB + (wn * 64 + ni * 16 + ln) * BK + quad * 8);

#pragma unroll
    for (int mi = 0; mi < 4; ++mi)
#pragma unroll
      for (int ni = 0; ni < 4; ++ni)
        acc[mi][ni] = __builtin_amdgcn_mfma_f32_16x16x32_bf16(af[mi], bfr[ni],
                                                              acc[mi][ni], 0, 0, 0);

    __syncthreads();  // protect LDS from next iteration's staging
  }

  // epilogue: C/D layout col = lane&15, row = quad*4 + reg (guide §3, verified)
#pragma unroll
  for (int ni = 0; ni < 4; ++ni) {
    const int n = n0 + wn * 64 + ni * 16 + ln;
    const float bv = bias[n];
#pragma unroll
    for (int mi = 0; mi < 4; ++mi) {
      const int mb = m0 + wm * 64 + mi * 16 + quad * 4;
#pragma unroll
      for (int r = 0; r < 4; ++r)
        C[(size_t)(mb + r) * N + n] = acc[mi][ni][r] + bv;
    }
  }
}

// ---------------- Fallback (only if ws too small): correct but slow ----------
__global__ __launch_bounds__(256) void fallback_kernel(
    const float* __restrict__ x, const float* __restrict__ centroids,
    const int* __restrict__ labels, const float* __restrict__ scale,
    const float* __restrict__ bias, float* __restrict__ out,
    int M, int N, int K, int G) {
  int idx = blockIdx.x * 256 + threadIdx.x;
  if (idx >= M * N) return;
  int m = idx / N, n = idx % N;
  float acc = 0.f;
  for (int k = 0; k < K; ++k) {
    int lab = labels[(size_t)k * G + (n >> 3)];
    float wv = centroids[(size_t)lab * 8 + (n & 7)] / fmaxf(scale[k], 1e-8f);
    acc += x[(size_t)m * K + k] * wv;
  }
  out[idx] = acc + bias[n];
}

extern "C" void kernel_launch(void* const* d_in, const int* in_sizes, int n_in,
                              void* d_out, int out_size, void* d_ws, size_t ws_size,
                              hipStream_t stream) {
  const float* x         = (const float*)d_in[0];
  const float* centroids = (const float*)d_in[1];
  const int*   labels    = (const int*)d_in[2];
  const float* scale     = (const float*)d_in[3];
  const float* bias      = (const float*)d_in[4];
  float* out = (float*)d_out;

  const int in_f  = in_sizes[3];         // 4096 (K)
  const int out_f = in_sizes[4];         // 4096 (N)
  const int M     = in_sizes[0] / in_f;  // 8192
  const int G     = in_sizes[2] / in_f;  // 512 groups per column
  const int K = in_f, N = out_f;

  size_t need = (size_t)M * K * 2 + (size_t)N * K * 2;  // ~100.7 MB
  if (ws_size < need) {
    int total = M * N;
    fallback_kernel<<<dim3((total + 255) / 256), 256, 0, stream>>>(
        x, centroids, labels, scale, bias, out, M, N, K, G);
    return;
  }

  unsigned short* Xb = (unsigned short*)d_ws;           // [M][K] bf16
  unsigned short* Bt = Xb + (size_t)M * K;              // [N][K] bf16

  int n4 = (M * K) / 4;
  cvt_x_kernel<<<dim3((n4 + 255) / 256), 256, 0, stream>>>((const float4*)x, (u16x4*)Xb, n4);
  dequant_kernel<<<dim3(K / 256, G), 256, 0, stream>>>(centroids, labels, scale, Bt, K, G);
  gemm_bias_kernel<<<dim3(N / BN, M / BM), 256, 0, stream>>>(Xb, Bt, bias, out, M, N, K);
}